// Round 1
// baseline (2973.383 us; speedup 1.0000x reference)
//
#include <hip/hip_runtime.h>
#include <hip/hip_bf16.h>

#define N_NODES 50000
#define N_EDGES 800000
#define HIDDEN 128
#define STATIC 16
#define EDGE_F 16
#define HEADS 8
#define KIN 304      // 2*128 + 2*16 + 16
#define WID 256
#define TILE 32      // edges per block

// ---------------------------------------------------------------------------
// Kernel 1: per-edge gate MLP + gated atomic scatter into agg (= d_out proj region)
// block = 256 threads, handles TILE=32 edges
// ---------------------------------------------------------------------------
__global__ __launch_bounds__(256, 2) void gate_scatter_kernel(
    const float* __restrict__ h, const float* __restrict__ xs,
    const int* __restrict__ ei, const float* __restrict__ ef,
    const float* __restrict__ W1, const float* __restrict__ W2,
    float* __restrict__ gates_out, float* __restrict__ agg)
{
    // buf serves as in_t[304][32] during the GEMM, then hid[32][257] after
    __shared__ float buf[KIN * TILE];          // 38912 B
    __shared__ float w1_t[WID][17];            // 17408 B (pad 17: kills 32-way conflict)
    __shared__ float w2_s[HEADS][257];         // 8224 B  (pad 257)
    __shared__ float gate_s[TILE][HEADS];      // 1024 B
    __shared__ int src_s[TILE];
    __shared__ int dst_s[TILE];

    const int tid = threadIdx.x;
    const int e0 = blockIdx.x * TILE;

    if (tid < TILE) {
        src_s[tid] = ei[N_EDGES + e0 + tid];   // src = edge_index[1]
        dst_s[tid] = ei[e0 + tid];             // dest = edge_index[0]
    }
    for (int i = tid; i < HEADS * WID; i += 256)
        w2_s[i >> 8][i & 255] = W2[i];
    __syncthreads();

    // ---- gather mlp_input transposed: in_t[p][e], float4 granularity ----
    // 76 float4-rows per edge: [0,32)=h[src], [32,64)=h[dest],
    // [64,68)=xs[src], [68,72)=xs[dest], [72,76)=ef[e]
    for (int idx = tid; idx < 76 * TILE; idx += 256) {
        int e = idx & (TILE - 1);
        int q = idx >> 5;
        const float* p;
        if (q < 32)      p = h  + (size_t)src_s[e] * HIDDEN + (q << 2);
        else if (q < 64) p = h  + (size_t)dst_s[e] * HIDDEN + ((q - 32) << 2);
        else if (q < 68) p = xs + (size_t)src_s[e] * STATIC + ((q - 64) << 2);
        else if (q < 72) p = xs + (size_t)dst_s[e] * STATIC + ((q - 68) << 2);
        else             p = ef + (size_t)(e0 + e) * EDGE_F + ((q - 72) << 2);
        float4 v = *(const float4*)p;
        int row = q << 2;
        buf[(row + 0) * TILE + e] = v.x;   // consecutive tid -> consecutive e:
        buf[(row + 1) * TILE + e] = v.y;   // contiguous LDS words, conflict-free
        buf[(row + 2) * TILE + e] = v.z;
        buf[(row + 3) * TILE + e] = v.w;
    }
    __syncthreads();

    // ---- hidden = relu(in @ W1.T): thread = 2 units x 16 edges ----
    const int u0 = (tid >> 1) * 2;         // units u0, u0+1
    const int eh = (tid & 1) * 16;         // edge half
    float acc0[16] = {0.f};
    float acc1[16] = {0.f};

    for (int k0 = 0; k0 < KIN; k0 += 16) {
        // stage W1[0:256][k0:k0+16] into LDS (coalesced float4 loads)
        for (int i = tid; i < 1024; i += 256) {
            int u = i >> 2;
            int kk = (i & 3) << 2;
            float4 w = *(const float4*)(W1 + (size_t)u * KIN + k0 + kk);
            w1_t[u][kk + 0] = w.x;
            w1_t[u][kk + 1] = w.y;
            w1_t[u][kk + 2] = w.z;
            w1_t[u][kk + 3] = w.w;
        }
        __syncthreads();
        #pragma unroll
        for (int kk = 0; kk < 16; ++kk) {
            float w0  = w1_t[u0][kk];
            float w1v = w1_t[u0 + 1][kk];
            const float* row = &buf[(k0 + kk) * TILE + eh];  // 64B-aligned
            #pragma unroll
            for (int j = 0; j < 16; j += 4) {
                float4 v = *(const float4*)(row + j);
                acc0[j + 0] += w0 * v.x;  acc1[j + 0] += w1v * v.x;
                acc0[j + 1] += w0 * v.y;  acc1[j + 1] += w1v * v.y;
                acc0[j + 2] += w0 * v.z;  acc1[j + 2] += w1v * v.z;
                acc0[j + 3] += w0 * v.w;  acc1[j + 3] += w1v * v.w;
            }
        }
        __syncthreads();   // all reads of w1_t done before next stage
    }

    // ---- write relu'd hidden into buf as hid[32][257] (in_t no longer needed) ----
    #pragma unroll
    for (int j = 0; j < 16; ++j) {
        int e = eh + j;
        buf[e * 257 + u0 + 0] = fmaxf(acc0[j], 0.f);
        buf[e * 257 + u0 + 1] = fmaxf(acc1[j], 0.f);
    }
    __syncthreads();

    // ---- scores + sigmoid: thread t -> (edge t>>3, head t&7) ----
    {
        int e = tid >> 3, hh = tid & 7;
        const float* hrow = &buf[e * 257];
        const float* wrow = &w2_s[hh][0];
        float sc = 0.f;
        #pragma unroll 8
        for (int k = 0; k < WID; ++k) sc += hrow[k] * wrow[k];
        float g = 1.f / (1.f + __expf(-sc));
        gate_s[e][hh] = g;
        gates_out[(size_t)e0 * HEADS + tid] = g;   // contiguous: e0*8 + e*8+hh
    }
    __syncthreads();

    // ---- gated scatter: gated = h[src] * gate[head]; atomicAdd into agg[dest] ----
    #pragma unroll
    for (int i = 0; i < 16; ++i) {
        int idx = tid + (i << 8);      // 0..4095
        int e = idx >> 7;
        int f = idx & 127;
        float val = h[(size_t)src_s[e] * HIDDEN + f] * gate_s[e][f >> 4];
        atomicAdd(&agg[(size_t)dst_s[e] * HIDDEN + f], val);
    }
}

// ---------------------------------------------------------------------------
// Kernel 2: projected = agg @ Wout.T, in place over the agg buffer (d_out)
// block = 256 threads, 32 nodes; rows staged in LDS before being overwritten
// ---------------------------------------------------------------------------
__global__ __launch_bounds__(256, 1) void proj_kernel(
    const float* __restrict__ Wout, float* __restrict__ out)
{
    __shared__ float wlds[HIDDEN][129];    // 66048 B (pad 129: conflict-free)
    __shared__ float aggs[32][HIDDEN];     // 16384 B
    const int tid = threadIdx.x;
    const int n0 = blockIdx.x * 32;

    for (int i = tid; i < HIDDEN * HIDDEN; i += 256)
        wlds[i >> 7][i & 127] = Wout[i];
    for (int i = tid; i < 32 * HIDDEN; i += 256) {
        int nl = i >> 7, f = i & 127;
        int n = n0 + nl;
        aggs[nl][f] = (n < N_NODES) ? out[(size_t)n * HIDDEN + f] : 0.f;
    }
    __syncthreads();

    for (int i = 0; i < 16; ++i) {
        int idx = tid + (i << 8);
        int nl = idx >> 7, o = idx & 127;
        float acc = 0.f;
        #pragma unroll 8
        for (int k = 0; k < HIDDEN; ++k) acc += aggs[nl][k] * wlds[o][k];
        int n = n0 + nl;
        if (n < N_NODES) out[(size_t)n * HIDDEN + o] = acc;
    }
}

// ---------------------------------------------------------------------------
extern "C" void kernel_launch(void* const* d_in, const int* in_sizes, int n_in,
                              void* d_out, int out_size, void* d_ws, size_t ws_size,
                              hipStream_t stream) {
    const float* h    = (const float*)d_in[0];
    const float* xs   = (const float*)d_in[1];
    const int*   ei   = (const int*)d_in[2];
    const float* ef   = (const float*)d_in[3];
    const float* W1   = (const float*)d_in[4];
    const float* W2   = (const float*)d_in[5];
    const float* Wout = (const float*)d_in[6];

    float* proj_out  = (float*)d_out;                        // [N, 128]
    float* gates_out = proj_out + (size_t)N_NODES * HIDDEN;  // [E, 8]

    // agg accumulates in the proj region; harness poisons d_out, so zero it
    hipMemsetAsync(proj_out, 0, (size_t)N_NODES * HIDDEN * sizeof(float), stream);

    gate_scatter_kernel<<<N_EDGES / TILE, 256, 0, stream>>>(
        h, xs, ei, ef, W1, W2, gates_out, proj_out);

    proj_kernel<<<(N_NODES + 31) / 32, 256, 0, stream>>>(Wout, proj_out);
}

// Round 2
// 2341.451 us; speedup vs baseline: 1.2699x; 1.2699x over previous
//
#include <hip/hip_runtime.h>
#include <hip/hip_bf16.h>

#define N_NODES 50000
#define N_EDGES 800000
#define HIDDEN 128
#define STATIC 16
#define EDGE_F 16
#define HEADS 8
#define KIN 304      // 2*128 + 2*16 + 16
#define KPAD 320     // KIN padded to multiple of 32
#define WID 256
#define TILE 64      // edges per block (MLP kernel)
#define AP 328       // A_lds row stride in bf16 elems (stride 656B -> 2-way bank alias, free)
#define BP 40        // B_lds row stride (80B -> 2-way alias, free)
#define HP 264       // hidden/W2 LDS row stride (528B, 16B-aligned, 2-way alias)

typedef short bf16x8 __attribute__((ext_vector_type(8)));
typedef unsigned short u16x4 __attribute__((ext_vector_type(4)));
typedef float f32x4 __attribute__((ext_vector_type(4)));

__device__ __forceinline__ unsigned short f2bf(float x) {
    __hip_bfloat16 b = __float2bfloat16(x);
    return __builtin_bit_cast(unsigned short, b);
}

// ---------------------------------------------------------------------------
// Prep: convert W1 [256][304] and W2 [8][256] fp32 -> bf16 into d_ws
// ---------------------------------------------------------------------------
__global__ void prep_kernel(const float* __restrict__ W1, const float* __restrict__ W2,
                            unsigned short* __restrict__ wb) {
    int i = blockIdx.x * 256 + threadIdx.x;          // 0 .. 79871
    if (i < WID * KIN) wb[i] = f2bf(W1[i]);
    else {
        int j = i - WID * KIN;
        if (j < HEADS * WID) wb[WID * KIN + j] = f2bf(W2[j]);
    }
}

// ---------------------------------------------------------------------------
// MLP kernel: per-edge gate MLP via bf16 MFMA. 64 edges/block, 256 threads.
// Writes gates [E][8] fp32.
// ---------------------------------------------------------------------------
__global__ __launch_bounds__(256, 2) void mlp_gates_kernel(
    const float* __restrict__ h, const float* __restrict__ xs,
    const int* __restrict__ ei, const float* __restrict__ ef,
    const unsigned short* __restrict__ wb,   // bf16 W1 [256][304], then W2 [8][256]
    float* __restrict__ gates_out)
{
    __shared__ short A_sh[TILE * AP];       // 41984 B; reused as hid[64][264] later
    __shared__ short B_sh[WID * BP];        // 20480 B (one 32-k chunk of W1^T)
    __shared__ short W2_sh[16 * HP];        //  8448 B ([16][264], rows 8..15 zero)
    __shared__ int src_s[TILE], dst_s[TILE];

    const int tid  = threadIdx.x;
    const int e0   = blockIdx.x * TILE;
    const int lane = tid & 63;
    const int w    = tid >> 6;              // wave id 0..3, owns edges [w*16, w*16+16)

    if (tid < TILE) {
        src_s[tid] = ei[N_EDGES + e0 + tid];   // src = edge_index[1]
        dst_s[tid] = ei[e0 + tid];             // dest = edge_index[0]
    }
    // W2 -> LDS [16][264] zero-padded (cols 256.., rows 8.. are zero)
    for (int i = tid; i < 16 * HP; i += 256) {
        int u = i / HP, c = i - u * HP;
        W2_sh[i] = (u < HEADS && c < WID) ? (short)wb[WID * KIN + u * WID + c] : (short)0;
    }
    __syncthreads();

    // ---- gather mlp_input -> A_sh bf16 [64][328], k padded to 320 with zeros ----
    {
        const float4* h4  = (const float4*)h;
        const float4* xs4 = (const float4*)xs;
        const float4* ef4 = (const float4*)ef;
        for (int idx = tid; idx < TILE * 80; idx += 256) {
            int e = idx & 63;
            int q = idx >> 6;                     // float4 index 0..79
            float4 v = make_float4(0.f, 0.f, 0.f, 0.f);
            if (q < 32)      v = h4[(size_t)src_s[e] * 32 + q];
            else if (q < 64) v = h4[(size_t)dst_s[e] * 32 + (q - 32)];
            else if (q < 68) v = xs4[(size_t)src_s[e] * 4 + (q - 64)];
            else if (q < 72) v = xs4[(size_t)dst_s[e] * 4 + (q - 68)];
            else if (q < 76) v = ef4[(size_t)(e0 + e) * 4 + (q - 72)];
            u16x4 p;
            p[0] = f2bf(v.x); p[1] = f2bf(v.y); p[2] = f2bf(v.z); p[3] = f2bf(v.w);
            *(u16x4*)(&A_sh[e * AP + 4 * q]) = p;   // 8B-aligned
        }
    }

    // ---- GEMM1: hidden[64][256] = A[64][320] @ W1^T[320][256], 10 k-chunks ----
    f32x4 acc[16];
    #pragma unroll
    for (int t = 0; t < 16; ++t) acc[t] = (f32x4)(0.f);

    for (int ks = 0; ks < KPAD / 32; ++ks) {
        const int k0 = ks * 32;
        // stage W1 chunk: B_sh[u][kk] = W1bf[u][k0+kk], zero past KIN
        for (int i = tid; i < 1024; i += 256) {
            int u   = i >> 2;
            int kk0 = (i & 3) << 3;
            int k   = k0 + kk0;
            bf16x8 v;
            if (k + 8 <= KIN) v = *(const bf16x8*)(wb + (size_t)u * KIN + k);
            else              v = (bf16x8)(short)0;
            *(bf16x8*)(&B_sh[u * BP + kk0]) = v;
        }
        __syncthreads();
        // A-frag: lane l -> row (l&15), 8 contiguous k at (l>>4)*8
        bf16x8 a = *(const bf16x8*)(&A_sh[(w * 16 + (lane & 15)) * AP + k0 + (lane >> 4) * 8]);
        #pragma unroll
        for (int t = 0; t < 16; ++t) {
            bf16x8 b = *(const bf16x8*)(&B_sh[(t * 16 + (lane & 15)) * BP + (lane >> 4) * 8]);
            acc[t] = __builtin_amdgcn_mfma_f32_16x16x32_bf16(a, b, acc[t], 0, 0, 0);
        }
        __syncthreads();    // all mfma reads done before restaging B (and before hid write)
    }

    // ---- relu + write hidden bf16 into A_sh reused as hid[64][264] ----
    short* hid = A_sh;
    #pragma unroll
    for (int t = 0; t < 16; ++t) {
        #pragma unroll
        for (int r = 0; r < 4; ++r) {
            int e = w * 16 + (lane >> 4) * 4 + r;   // C/D: row=(lane>>4)*4+reg
            int n = t * 16 + (lane & 15);           //      col=lane&15
            hid[e * HP + n] = (short)f2bf(fmaxf(acc[t][r], 0.f));
        }
    }
    __syncthreads();

    // ---- GEMM2: scores[64][8] = hid[64][256] @ W2^T, one 16-col tile ----
    f32x4 acc2 = (f32x4)(0.f);
    #pragma unroll
    for (int k2 = 0; k2 < 8; ++k2) {
        bf16x8 a2 = *(const bf16x8*)(&hid[(w * 16 + (lane & 15)) * HP + k2 * 32 + (lane >> 4) * 8]);
        bf16x8 b2 = *(const bf16x8*)(&W2_sh[(lane & 15) * HP + k2 * 32 + (lane >> 4) * 8]);
        acc2 = __builtin_amdgcn_mfma_f32_16x16x32_bf16(a2, b2, acc2, 0, 0, 0);
    }
    int head = lane & 15;
    if (head < HEADS) {
        #pragma unroll
        for (int r = 0; r < 4; ++r) {
            int e = e0 + w * 16 + (lane >> 4) * 4 + r;
            float g = 1.f / (1.f + __expf(-acc2[r]));
            gates_out[(size_t)e * HEADS + head] = g;
        }
    }
}

// ---------------------------------------------------------------------------
// Scatter: gated = h[src] * gates -> atomicAdd into agg[dest]. fp32 throughout.
// 32 threads per edge, 4 feats per thread.
// ---------------------------------------------------------------------------
__global__ __launch_bounds__(256) void scatter_kernel(
    const float* __restrict__ h, const int* __restrict__ ei,
    const float* __restrict__ gates, float* __restrict__ agg)
{
    int gid = blockIdx.x * 256 + threadIdx.x;      // 0 .. 25.6M-1
    int e  = gid >> 5;
    int f0 = (gid & 31) << 2;                      // 0,4,...,124 (same head group of 16)
    int s = ei[N_EDGES + e];
    int d = ei[e];
    float g = gates[(size_t)e * HEADS + (f0 >> 4)];
    float4 v = *(const float4*)(h + (size_t)s * HIDDEN + f0);
    float* out = agg + (size_t)d * HIDDEN + f0;
    atomicAdd(out + 0, v.x * g);
    atomicAdd(out + 1, v.y * g);
    atomicAdd(out + 2, v.z * g);
    atomicAdd(out + 3, v.w * g);
}

// ---------------------------------------------------------------------------
// Projection: projected = agg @ Wout.T, in place over d_out proj region.
// ---------------------------------------------------------------------------
__global__ __launch_bounds__(256, 1) void proj_kernel(
    const float* __restrict__ Wout, float* __restrict__ out)
{
    __shared__ float wlds[HIDDEN][129];
    __shared__ float aggs[32][HIDDEN];
    const int tid = threadIdx.x;
    const int n0 = blockIdx.x * 32;

    for (int i = tid; i < HIDDEN * HIDDEN; i += 256)
        wlds[i >> 7][i & 127] = Wout[i];
    for (int i = tid; i < 32 * HIDDEN; i += 256) {
        int nl = i >> 7, f = i & 127;
        int n = n0 + nl;
        aggs[nl][f] = (n < N_NODES) ? out[(size_t)n * HIDDEN + f] : 0.f;
    }
    __syncthreads();

    for (int i = 0; i < 16; ++i) {
        int idx = tid + (i << 8);
        int nl = idx >> 7, o = idx & 127;
        float acc = 0.f;
        #pragma unroll 8
        for (int k = 0; k < HIDDEN; ++k) acc += aggs[nl][k] * wlds[o][k];
        int n = n0 + nl;
        if (n < N_NODES) out[(size_t)n * HIDDEN + o] = acc;
    }
}

// ---------------------------------------------------------------------------
extern "C" void kernel_launch(void* const* d_in, const int* in_sizes, int n_in,
                              void* d_out, int out_size, void* d_ws, size_t ws_size,
                              hipStream_t stream) {
    const float* h    = (const float*)d_in[0];
    const float* xs   = (const float*)d_in[1];
    const int*   ei   = (const int*)d_in[2];
    const float* ef   = (const float*)d_in[3];
    const float* W1   = (const float*)d_in[4];
    const float* W2   = (const float*)d_in[5];
    const float* Wout = (const float*)d_in[6];

    float* proj_out  = (float*)d_out;                        // [N, 128]
    float* gates_out = proj_out + (size_t)N_NODES * HIDDEN;  // [E, 8]
    unsigned short* wb = (unsigned short*)d_ws;              // 160 KB bf16 weights

    prep_kernel<<<312, 256, 0, stream>>>(W1, W2, wb);
    hipMemsetAsync(proj_out, 0, (size_t)N_NODES * HIDDEN * sizeof(float), stream);

    mlp_gates_kernel<<<N_EDGES / TILE, 256, 0, stream>>>(h, xs, ei, ef, wb, gates_out);

    scatter_kernel<<<(N_EDGES * 32) / 256, 256, 0, stream>>>(h, ei, gates_out, proj_out);

    proj_kernel<<<(N_NODES + 31) / 32, 256, 0, stream>>>(Wout, proj_out);
}

// Round 3
// 1334.979 us; speedup vs baseline: 2.2273x; 1.7539x over previous
//
#include <hip/hip_runtime.h>
#include <hip/hip_bf16.h>

#define N_NODES 50000
#define N_EDGES 800000
#define HIDDEN 128
#define STATIC 16
#define EDGE_F 16
#define HEADS 8
#define KIN 304      // 2*128 + 2*16 + 16
#define KPAD 320     // KIN padded to multiple of 32
#define WID 256
#define TILE 64      // edges per block (MLP kernel)
#define AP 328       // A_lds row stride in bf16 elems (2-way bank alias, free)
#define BP 40        // B_lds row stride
#define HP 264       // hidden/W2 LDS row stride

typedef short bf16x8 __attribute__((ext_vector_type(8)));
typedef unsigned short u16x4 __attribute__((ext_vector_type(4)));
typedef float f32x4 __attribute__((ext_vector_type(4)));

__device__ __forceinline__ unsigned short f2bf(float x) {
    __hip_bfloat16 b = __float2bfloat16(x);
    return __builtin_bit_cast(unsigned short, b);
}

// ---------------------------------------------------------------------------
// Prep: convert W1 [256][304] and W2 [8][256] fp32 -> bf16 into d_ws
// ---------------------------------------------------------------------------
__global__ void prep_kernel(const float* __restrict__ W1, const float* __restrict__ W2,
                            unsigned short* __restrict__ wb) {
    int i = blockIdx.x * 256 + threadIdx.x;          // 0 .. 79871
    if (i < WID * KIN) wb[i] = f2bf(W1[i]);
    else {
        int j = i - WID * KIN;
        if (j < HEADS * WID) wb[WID * KIN + j] = f2bf(W2[j]);
    }
}

// ---------------------------------------------------------------------------
// MLP kernel: per-edge gate MLP via bf16 MFMA. 64 edges/block, 256 threads.
// ---------------------------------------------------------------------------
__global__ __launch_bounds__(256, 2) void mlp_gates_kernel(
    const float* __restrict__ h, const float* __restrict__ xs,
    const int* __restrict__ ei, const float* __restrict__ ef,
    const unsigned short* __restrict__ wb,   // bf16 W1 [256][304], then W2 [8][256]
    float* __restrict__ gates_out)
{
    __shared__ short A_sh[TILE * AP];       // 41984 B; reused as hid[64][264] later
    __shared__ short B_sh[WID * BP];        // 20480 B (one 32-k chunk of W1^T)
    __shared__ short W2_sh[16 * HP];        //  8448 B ([16][264], rows 8..15 zero)
    __shared__ int src_s[TILE], dst_s[TILE];

    const int tid  = threadIdx.x;
    const int e0   = blockIdx.x * TILE;
    const int lane = tid & 63;
    const int w    = tid >> 6;              // wave id 0..3, owns edges [w*16, w*16+16)

    if (tid < TILE) {
        src_s[tid] = ei[N_EDGES + e0 + tid];   // src = edge_index[1]
        dst_s[tid] = ei[e0 + tid];             // dest = edge_index[0]
    }
    for (int i = tid; i < 16 * HP; i += 256) {
        int u = i / HP, c = i - u * HP;
        W2_sh[i] = (u < HEADS && c < WID) ? (short)wb[WID * KIN + u * WID + c] : (short)0;
    }
    __syncthreads();

    // ---- gather mlp_input -> A_sh bf16 [64][328], k padded to 320 with zeros ----
    {
        const float4* h4  = (const float4*)h;
        const float4* xs4 = (const float4*)xs;
        const float4* ef4 = (const float4*)ef;
        for (int idx = tid; idx < TILE * 80; idx += 256) {
            int e = idx & 63;
            int q = idx >> 6;                     // float4 index 0..79
            float4 v = make_float4(0.f, 0.f, 0.f, 0.f);
            if (q < 32)      v = h4[(size_t)src_s[e] * 32 + q];
            else if (q < 64) v = h4[(size_t)dst_s[e] * 32 + (q - 32)];
            else if (q < 68) v = xs4[(size_t)src_s[e] * 4 + (q - 64)];
            else if (q < 72) v = xs4[(size_t)dst_s[e] * 4 + (q - 68)];
            else if (q < 76) v = ef4[(size_t)(e0 + e) * 4 + (q - 72)];
            u16x4 p;
            p[0] = f2bf(v.x); p[1] = f2bf(v.y); p[2] = f2bf(v.z); p[3] = f2bf(v.w);
            *(u16x4*)(&A_sh[e * AP + 4 * q]) = p;   // 8B-aligned
        }
    }

    // ---- GEMM1: hidden[64][256] = A[64][320] @ W1^T[320][256], 10 k-chunks ----
    f32x4 acc[16];
    #pragma unroll
    for (int t = 0; t < 16; ++t) acc[t] = (f32x4)(0.f);

    for (int ks = 0; ks < KPAD / 32; ++ks) {
        const int k0 = ks * 32;
        for (int i = tid; i < 1024; i += 256) {
            int u   = i >> 2;
            int kk0 = (i & 3) << 3;
            int k   = k0 + kk0;
            bf16x8 v;
            if (k + 8 <= KIN) v = *(const bf16x8*)(wb + (size_t)u * KIN + k);
            else              v = (bf16x8)(short)0;
            *(bf16x8*)(&B_sh[u * BP + kk0]) = v;
        }
        __syncthreads();
        bf16x8 a = *(const bf16x8*)(&A_sh[(w * 16 + (lane & 15)) * AP + k0 + (lane >> 4) * 8]);
        #pragma unroll
        for (int t = 0; t < 16; ++t) {
            bf16x8 b = *(const bf16x8*)(&B_sh[(t * 16 + (lane & 15)) * BP + (lane >> 4) * 8]);
            acc[t] = __builtin_amdgcn_mfma_f32_16x16x32_bf16(a, b, acc[t], 0, 0, 0);
        }
        __syncthreads();
    }

    // ---- relu + write hidden bf16 into A_sh reused as hid[64][264] ----
    short* hid = A_sh;
    #pragma unroll
    for (int t = 0; t < 16; ++t) {
        #pragma unroll
        for (int r = 0; r < 4; ++r) {
            int e = w * 16 + (lane >> 4) * 4 + r;   // C/D: row=(lane>>4)*4+reg
            int n = t * 16 + (lane & 15);           //      col=lane&15
            hid[e * HP + n] = (short)f2bf(fmaxf(acc[t][r], 0.f));
        }
    }
    __syncthreads();

    // ---- GEMM2: scores[64][8] = hid[64][256] @ W2^T, one 16-col tile ----
    f32x4 acc2 = (f32x4)(0.f);
    #pragma unroll
    for (int k2 = 0; k2 < 8; ++k2) {
        bf16x8 a2 = *(const bf16x8*)(&hid[(w * 16 + (lane & 15)) * HP + k2 * 32 + (lane >> 4) * 8]);
        bf16x8 b2 = *(const bf16x8*)(&W2_sh[(lane & 15) * HP + k2 * 32 + (lane >> 4) * 8]);
        acc2 = __builtin_amdgcn_mfma_f32_16x16x32_bf16(a2, b2, acc2, 0, 0, 0);
    }
    int head = lane & 15;
    if (head < HEADS) {
        #pragma unroll
        for (int r = 0; r < 4; ++r) {
            int e = e0 + w * 16 + (lane >> 4) * 4 + r;
            float g = 1.f / (1.f + __expf(-acc2[r]));
            gates_out[(size_t)e * HEADS + head] = g;
        }
    }
}

// ---------------------------------------------------------------------------
// CSR build: histogram of dest, prefix scan, slot allocation
// ---------------------------------------------------------------------------
__global__ void hist_kernel(const int* __restrict__ ei, int* __restrict__ deg) {
    int e = blockIdx.x * 256 + threadIdx.x;
    if (e < N_EDGES) atomicAdd(&deg[ei[e]], 1);    // dest = edge_index[0]
}

#define SCAN_T 256
#define SCAN_CHUNK 196   // 256*196 = 50176 >= 50000
__global__ __launch_bounds__(SCAN_T) void scan_kernel(
    const int* __restrict__ deg, int* __restrict__ offs, int* __restrict__ cursor) {
    __shared__ int part[SCAN_T];
    int t = threadIdx.x;
    int b = t * SCAN_CHUNK;
    int s = 0;
    for (int i = 0; i < SCAN_CHUNK; ++i) {
        int idx = b + i;
        if (idx < N_NODES) s += deg[idx];
    }
    part[t] = s;
    __syncthreads();
    for (int off = 1; off < SCAN_T; off <<= 1) {
        int v = (t >= off) ? part[t - off] : 0;
        __syncthreads();
        part[t] += v;
        __syncthreads();
    }
    int run = (t == 0) ? 0 : part[t - 1];           // exclusive base
    for (int i = 0; i < SCAN_CHUNK; ++i) {
        int idx = b + i;
        if (idx < N_NODES) {
            int dv = deg[idx];
            offs[idx] = run;
            cursor[idx] = run;
            run += dv;
        }
    }
    if (t == SCAN_T - 1) offs[N_NODES] = run;
}

__global__ void permute_kernel(const int* __restrict__ ei, int* __restrict__ cursor,
                               int* __restrict__ perm) {
    int e = blockIdx.x * 256 + threadIdx.x;
    if (e < N_EDGES) {
        int d = ei[e];
        int pos = atomicAdd(&cursor[d], 1);
        perm[pos] = e;
    }
}

// ---------------------------------------------------------------------------
// Segmented aggregation: one wave per dest node, no atomics.
// lane owns features [2*lane, 2*lane+1]; head = feature/16.
// ---------------------------------------------------------------------------
__global__ __launch_bounds__(256) void agg_csr_kernel(
    const float* __restrict__ h, const int* __restrict__ ei,
    const float* __restrict__ gates, const int* __restrict__ offs,
    const int* __restrict__ perm, float* __restrict__ agg)
{
    int d = (blockIdx.x * 256 + threadIdx.x) >> 6;   // dest node = global wave id
    if (d >= N_NODES) return;
    int lane = threadIdx.x & 63;
    int f = lane << 1;
    int beg = offs[d], end = offs[d + 1];
    float accx = 0.f, accy = 0.f;
    for (int j = beg; j < end; ++j) {
        int e = perm[j];
        int s = ei[N_EDGES + e];                     // src = edge_index[1]
        float g = gates[(size_t)e * HEADS + (f >> 4)];
        float2 v = *(const float2*)(h + (size_t)s * HIDDEN + f);
        accx += v.x * g;
        accy += v.y * g;
    }
    float2 r; r.x = accx; r.y = accy;
    *(float2*)(agg + (size_t)d * HIDDEN + f) = r;    // plain store, no memset needed
}

// ---------------------------------------------------------------------------
// Fallback scatter (atomic) — used only if ws_size is too small for CSR
// ---------------------------------------------------------------------------
__global__ __launch_bounds__(256) void scatter_kernel(
    const float* __restrict__ h, const int* __restrict__ ei,
    const float* __restrict__ gates, float* __restrict__ agg)
{
    int gid = blockIdx.x * 256 + threadIdx.x;
    int e  = gid >> 5;
    int f0 = (gid & 31) << 2;
    int s = ei[N_EDGES + e];
    int d = ei[e];
    float g = gates[(size_t)e * HEADS + (f0 >> 4)];
    float4 v = *(const float4*)(h + (size_t)s * HIDDEN + f0);
    float* out = agg + (size_t)d * HIDDEN + f0;
    atomicAdd(out + 0, v.x * g);
    atomicAdd(out + 1, v.y * g);
    atomicAdd(out + 2, v.z * g);
    atomicAdd(out + 3, v.w * g);
}

// ---------------------------------------------------------------------------
// Projection: projected = agg @ Wout.T, in place over d_out proj region.
// ---------------------------------------------------------------------------
__global__ __launch_bounds__(256, 1) void proj_kernel(
    const float* __restrict__ Wout, float* __restrict__ out)
{
    __shared__ float wlds[HIDDEN][129];
    __shared__ float aggs[32][HIDDEN];
    const int tid = threadIdx.x;
    const int n0 = blockIdx.x * 32;

    for (int i = tid; i < HIDDEN * HIDDEN; i += 256)
        wlds[i >> 7][i & 127] = Wout[i];
    for (int i = tid; i < 32 * HIDDEN; i += 256) {
        int nl = i >> 7, f = i & 127;
        int n = n0 + nl;
        aggs[nl][f] = (n < N_NODES) ? out[(size_t)n * HIDDEN + f] : 0.f;
    }
    __syncthreads();

    for (int i = 0; i < 16; ++i) {
        int idx = tid + (i << 8);
        int nl = idx >> 7, o = idx & 127;
        float acc = 0.f;
        #pragma unroll 8
        for (int k = 0; k < HIDDEN; ++k) acc += aggs[nl][k] * wlds[o][k];
        int n = n0 + nl;
        if (n < N_NODES) out[(size_t)n * HIDDEN + o] = acc;
    }
}

// ---------------------------------------------------------------------------
extern "C" void kernel_launch(void* const* d_in, const int* in_sizes, int n_in,
                              void* d_out, int out_size, void* d_ws, size_t ws_size,
                              hipStream_t stream) {
    const float* h    = (const float*)d_in[0];
    const float* xs   = (const float*)d_in[1];
    const int*   ei   = (const int*)d_in[2];
    const float* ef   = (const float*)d_in[3];
    const float* W1   = (const float*)d_in[4];
    const float* W2   = (const float*)d_in[5];
    const float* Wout = (const float*)d_in[6];

    float* proj_out  = (float*)d_out;                        // [N, 128]
    float* gates_out = proj_out + (size_t)N_NODES * HIDDEN;  // [E, 8]

    // workspace layout
    const size_t WB_OFF     = 0;                 // bf16 weights, 159744 B
    const size_t DEG_OFF    = 163840;            // int[50000]
    const size_t OFFS_OFF   = DEG_OFF + 200064;  // int[50001]
    const size_t CURSOR_OFF = OFFS_OFF + 200064; // int[50000]
    const size_t PERM_OFF   = CURSOR_OFF + 200064; // int[800000]
    const size_t NEEDED     = PERM_OFF + 3200000;

    unsigned short* wb = (unsigned short*)((char*)d_ws + WB_OFF);

    prep_kernel<<<312, 256, 0, stream>>>(W1, W2, wb);

    mlp_gates_kernel<<<N_EDGES / TILE, 256, 0, stream>>>(h, xs, ei, ef, wb, gates_out);

    if (ws_size >= NEEDED) {
        int* deg    = (int*)((char*)d_ws + DEG_OFF);
        int* offs   = (int*)((char*)d_ws + OFFS_OFF);
        int* cursor = (int*)((char*)d_ws + CURSOR_OFF);
        int* perm   = (int*)((char*)d_ws + PERM_OFF);

        hipMemsetAsync(deg, 0, N_NODES * sizeof(int), stream);
        hist_kernel<<<(N_EDGES + 255) / 256, 256, 0, stream>>>(ei, deg);
        scan_kernel<<<1, SCAN_T, 0, stream>>>(deg, offs, cursor);
        permute_kernel<<<(N_EDGES + 255) / 256, 256, 0, stream>>>(ei, cursor, perm);
        agg_csr_kernel<<<(N_NODES * 64 + 255) / 256, 256, 0, stream>>>(
            h, ei, gates_out, offs, perm, proj_out);
    } else {
        hipMemsetAsync(proj_out, 0, (size_t)N_NODES * HIDDEN * sizeof(float), stream);
        scatter_kernel<<<(N_EDGES * 32) / 256, 256, 0, stream>>>(h, ei, gates_out, proj_out);
    }

    proj_kernel<<<(N_NODES + 31) / 32, 256, 0, stream>>>(Wout, proj_out);
}

// Round 4
// 1045.235 us; speedup vs baseline: 2.8447x; 1.2772x over previous
//
#include <hip/hip_runtime.h>
#include <hip/hip_bf16.h>

#define N_NODES 50000
#define N_EDGES 800000
#define HIDDEN 128
#define STATIC 16
#define EDGE_F 16
#define HEADS 8
#define KIN 304       // 2*128 + 2*16 + 16
#define KPAD 320      // KIN padded to multiple of 32
#define WID 256
#define TILE 64       // edges per tile
#define NTILES (N_EDGES / TILE)   // 12500
#define NB 512        // persistent blocks for mlp

typedef short bf16x8 __attribute__((ext_vector_type(8)));
typedef unsigned short u16x4 __attribute__((ext_vector_type(4)));
typedef unsigned short u16x8 __attribute__((ext_vector_type(8)));
typedef float f32x4 __attribute__((ext_vector_type(4)));

__device__ __forceinline__ unsigned short f2bf(float x) {
    __hip_bfloat16 b = __float2bfloat16(x);
    return __builtin_bit_cast(unsigned short, b);
}

// ---------------------------------------------------------------------------
// prep_weights: W1 -> wb1p[256][320] bf16 (zero-padded), W2 -> wb2p[16][256]
// ---------------------------------------------------------------------------
__global__ void prep_weights_kernel(const float* __restrict__ W1,
                                    const float* __restrict__ W2,
                                    unsigned short* __restrict__ wb1p,
                                    unsigned short* __restrict__ wb2p) {
    int gi = blockIdx.x * 256 + threadIdx.x;    // 8-elem group id
    if (gi < WID * (KPAD / 8)) {                // 10240 groups
        int row = gi / 40, kg = gi - row * 40;
        u16x8 o = (u16x8)0;
        if (kg < 38) {                          // 38*8 = 304 = KIN exactly
            const float* s = W1 + (size_t)row * KIN + kg * 8;
            #pragma unroll
            for (int i = 0; i < 8; ++i) o[i] = f2bf(s[i]);
        }
        *(u16x8*)(wb1p + (size_t)gi * 8) = o;
    } else {
        int gj = gi - WID * (KPAD / 8);
        if (gj < 16 * 32) {                     // 512 groups
            int row = gj >> 5, kg = gj & 31;
            u16x8 o = (u16x8)0;
            if (row < HEADS) {
                const float* s = W2 + (size_t)row * WID + kg * 8;
                #pragma unroll
                for (int i = 0; i < 8; ++i) o[i] = f2bf(s[i]);
            }
            *(u16x8*)(wb2p + (size_t)gj * 8) = o;
        }
    }
}

// ---------------------------------------------------------------------------
// prep_data: h, xs, ef fp32 -> bf16 copies (streaming)
// ---------------------------------------------------------------------------
#define HB_G  (N_NODES * HIDDEN / 8)    // 800000
#define XSB_G (N_NODES * STATIC / 8)    // 100000
#define EFB_G (N_EDGES * EDGE_F / 8)    // 1600000
__global__ void prep_data_kernel(const float* __restrict__ h,
                                 const float* __restrict__ xs,
                                 const float* __restrict__ ef,
                                 unsigned short* __restrict__ hb,
                                 unsigned short* __restrict__ xsb,
                                 unsigned short* __restrict__ efb) {
    size_t gi = (size_t)blockIdx.x * 256 + threadIdx.x;
    const float* s;
    unsigned short* d;
    if (gi < HB_G)                    { s = h  + gi * 8;              d = hb  + gi * 8; }
    else if (gi < HB_G + XSB_G)       { size_t k = gi - HB_G;         s = xs + k * 8; d = xsb + k * 8; }
    else if (gi < HB_G + XSB_G + EFB_G) { size_t k = gi - HB_G - XSB_G; s = ef + k * 8; d = efb + k * 8; }
    else return;
    u16x8 o;
    #pragma unroll
    for (int i = 0; i < 8; ++i) o[i] = f2bf(s[i]);
    *(u16x8*)d = o;
}

// ---------------------------------------------------------------------------
// MLP: weight-stationary register GEMM. Persistent blocks, grid-stride tiles.
// Wave w owns output units [64w,64w+64). A/hid LDS XOR-swizzled (T2).
// ---------------------------------------------------------------------------
template <bool PRE>
__global__ __launch_bounds__(256, 2) void mlp_gates_kernel(
    const float* __restrict__ hf, const float* __restrict__ xsf,
    const int* __restrict__ ei, const float* __restrict__ eff,
    const unsigned short* __restrict__ wb1p, const unsigned short* __restrict__ wb2p,
    const unsigned short* __restrict__ hb, const unsigned short* __restrict__ xsb,
    const unsigned short* __restrict__ efb,
    float* __restrict__ gates_out)
{
    __shared__ __align__(16) short A_sh[TILE * KPAD];    // 40960 B, row=640 B swizzled
    __shared__ __align__(16) short hid_sh[TILE * WID];   // 32768 B, row=512 B swizzled
    __shared__ int src_s[TILE], dst_s[TILE];

    const int tid  = threadIdx.x;
    const int lane = tid & 63;
    const int w    = tid >> 6;            // wave 0..3
    const int r    = lane & 15;
    const int g    = lane >> 4;
    const int xorv = (r & 7) << 4;        // T2 swizzle term for frag reads

    // ---- register-stationary weights: W1 frags 160 VGPR, W2 frags 32 VGPR ----
    bf16x8 b1[4][10];
    #pragma unroll
    for (int t = 0; t < 4; ++t)
        #pragma unroll
        for (int ks = 0; ks < 10; ++ks)
            b1[t][ks] = *(const bf16x8*)(wb1p + (size_t)((w * 4 + t) * 16 + r) * KPAD + ks * 32 + g * 8);
    bf16x8 w2f[8];
    #pragma unroll
    for (int k2 = 0; k2 < 8; ++k2)
        w2f[k2] = *(const bf16x8*)(wb2p + (size_t)r * WID + k2 * 32 + g * 8);

    int tile = blockIdx.x;
    if (tid < TILE && tile < NTILES) {
        src_s[tid] = ei[N_EDGES + tile * TILE + tid];   // src = edge_index[1]
        dst_s[tid] = ei[tile * TILE + tid];             // dest = edge_index[0]
    }
    __syncthreads();

    for (; tile < NTILES; tile += NB) {
        const int e0 = tile * TILE;

        // ---- gather mlp_input -> A_sh (bf16, swizzled) ----
        if (PRE) {
            const u16x8* h8  = (const u16x8*)hb;
            const u16x8* xs8 = (const u16x8*)xsb;
            const u16x8* ef8 = (const u16x8*)efb;
            #pragma unroll
            for (int idx = tid; idx < 1024; idx += 256) {       // h[src]: elems 0..127
                int e = idx >> 4, c = idx & 15;
                u16x8 v = h8[(size_t)src_s[e] * 16 + c];
                *(u16x8*)((char*)A_sh + e * 640 + (((c << 4)) ^ ((e & 7) << 4))) = v;
            }
            #pragma unroll
            for (int idx = tid; idx < 1024; idx += 256) {       // h[dest]: elems 128..255
                int e = idx >> 4, c = idx & 15;
                u16x8 v = h8[(size_t)dst_s[e] * 16 + c];
                *(u16x8*)((char*)A_sh + e * 640 + ((256 + (c << 4)) ^ ((e & 7) << 4))) = v;
            }
            #pragma unroll
            for (int idx = tid; idx < 512; idx += 256) {        // xs/ef/zero: elems 256..319
                int e = idx >> 3, c = idx & 7;
                u16x8 v = (u16x8)0;
                if (c < 2)      v = xs8[(size_t)src_s[e] * 2 + c];
                else if (c < 4) v = xs8[(size_t)dst_s[e] * 2 + (c - 2)];
                else if (c < 6) v = ef8[(size_t)(e0 + e) * 2 + (c - 4)];
                *(u16x8*)((char*)A_sh + e * 640 + ((512 + (c << 4)) ^ ((e & 7) << 4))) = v;
            }
        } else {
            const float4* h4  = (const float4*)hf;
            const float4* xs4 = (const float4*)xsf;
            const float4* ef4 = (const float4*)eff;
            #pragma unroll
            for (int idx = tid; idx < 2048; idx += 256) {       // h[src]
                int e = idx >> 5, q = idx & 31;
                float4 v = h4[(size_t)src_s[e] * 32 + q];
                u16x4 p; p[0] = f2bf(v.x); p[1] = f2bf(v.y); p[2] = f2bf(v.z); p[3] = f2bf(v.w);
                *(u16x4*)((char*)A_sh + e * 640 + (((q << 3)) ^ ((e & 7) << 4))) = p;
            }
            #pragma unroll
            for (int idx = tid; idx < 2048; idx += 256) {       // h[dest]
                int e = idx >> 5, q = idx & 31;
                float4 v = h4[(size_t)dst_s[e] * 32 + q];
                u16x4 p; p[0] = f2bf(v.x); p[1] = f2bf(v.y); p[2] = f2bf(v.z); p[3] = f2bf(v.w);
                *(u16x4*)((char*)A_sh + e * 640 + ((256 + (q << 3)) ^ ((e & 7) << 4))) = p;
            }
            #pragma unroll
            for (int idx = tid; idx < 1024; idx += 256) {       // xs/ef/zero
                int e = idx >> 4, c = idx & 15;
                float4 v = make_float4(0.f, 0.f, 0.f, 0.f);
                if (c < 4)       v = xs4[(size_t)src_s[e] * 4 + c];
                else if (c < 8)  v = xs4[(size_t)dst_s[e] * 4 + (c - 4)];
                else if (c < 12) v = ef4[(size_t)(e0 + e) * 4 + (c - 8)];
                u16x4 p; p[0] = f2bf(v.x); p[1] = f2bf(v.y); p[2] = f2bf(v.z); p[3] = f2bf(v.w);
                *(u16x4*)((char*)A_sh + e * 640 + ((512 + (c << 3)) ^ ((e & 7) << 4))) = p;
            }
        }
        __syncthreads();                                        // B1: A ready

        // preload next tile's indices (latency hides under GEMM1)
        int nsrc = 0, ndst = 0;
        const int ntile = tile + NB;
        const bool more = (ntile < NTILES);
        if (tid < TILE && more) {
            nsrc = ei[N_EDGES + ntile * TILE + tid];
            ndst = ei[ntile * TILE + tid];
        }

        // ---- GEMM1: 4 edge-subtiles x 4 unit-tiles x 10 k-chunks ----
        #pragma unroll
        for (int sub = 0; sub < 4; ++sub) {
            f32x4 acc[4];
            #pragma unroll
            for (int t = 0; t < 4; ++t) acc[t] = (f32x4)(0.f);
            const char* abase = (const char*)A_sh + (sub * 16 + r) * 640;
            #pragma unroll
            for (int ks = 0; ks < 10; ++ks) {
                bf16x8 a = *(const bf16x8*)(abase + (((ks << 6) | (g << 4)) ^ xorv));
                #pragma unroll
                for (int t = 0; t < 4; ++t)
                    acc[t] = __builtin_amdgcn_mfma_f32_16x16x32_bf16(a, b1[t][ks], acc[t], 0, 0, 0);
            }
            // relu + bf16 -> hid (C/D: col=lane&15 -> unit, row=g*4+q -> edge)
            #pragma unroll
            for (int t = 0; t < 4; ++t)
                #pragma unroll
                for (int q = 0; q < 4; ++q) {
                    int e = sub * 16 + g * 4 + q;
                    int n = (w * 4 + t) * 16 + r;
                    *(short*)((char*)hid_sh + e * 512 + ((n * 2) ^ ((e & 7) << 4))) =
                        (short)f2bf(fmaxf(acc[t][q], 0.f));
                }
        }
        if (tid < TILE && more) { src_s[tid] = nsrc; dst_s[tid] = ndst; }
        __syncthreads();                                        // B2: hid + indices ready

        // ---- GEMM2: wave w does its 16-edge subtile vs W2 frags ----
        f32x4 sacc = (f32x4)(0.f);
        const char* hbase = (const char*)hid_sh + (w * 16 + r) * 512;
        #pragma unroll
        for (int k2 = 0; k2 < 8; ++k2) {
            bf16x8 a2 = *(const bf16x8*)(hbase + (((k2 << 6) | (g << 4)) ^ xorv));
            sacc = __builtin_amdgcn_mfma_f32_16x16x32_bf16(a2, w2f[k2], sacc, 0, 0, 0);
        }
        if (r < HEADS) {
            #pragma unroll
            for (int q = 0; q < 4; ++q) {
                int e = e0 + w * 16 + g * 4 + q;
                gates_out[(size_t)e * HEADS + r] = 1.f / (1.f + __expf(-sacc[q]));
            }
        }
        // next gather may start immediately: every wave passed B2 => GEMM1 reads done
    }
}

// ---------------------------------------------------------------------------
// CSR build
// ---------------------------------------------------------------------------
__global__ void hist_kernel(const int* __restrict__ ei, int* __restrict__ deg) {
    int e = blockIdx.x * 256 + threadIdx.x;
    if (e < N_EDGES) atomicAdd(&deg[ei[e]], 1);
}

#define SCAN_T 1024
#define SCAN_CHUNK 49   // 1024*49 = 50176 >= 50000
__global__ __launch_bounds__(SCAN_T) void scan_kernel(
    const int* __restrict__ deg, int* __restrict__ offs, int* __restrict__ cursor) {
    __shared__ int part[SCAN_T];
    int t = threadIdx.x;
    int b = t * SCAN_CHUNK;
    int s = 0;
    for (int i = 0; i < SCAN_CHUNK; ++i) {
        int idx = b + i;
        if (idx < N_NODES) s += deg[idx];
    }
    part[t] = s;
    __syncthreads();
    for (int off = 1; off < SCAN_T; off <<= 1) {
        int v = (t >= off) ? part[t - off] : 0;
        __syncthreads();
        part[t] += v;
        __syncthreads();
    }
    int run = (t == 0) ? 0 : part[t - 1];
    for (int i = 0; i < SCAN_CHUNK; ++i) {
        int idx = b + i;
        if (idx < N_NODES) {
            int dv = deg[idx];
            offs[idx] = run;
            cursor[idx] = run;
            run += dv;
        }
    }
    if (t == SCAN_T - 1) offs[N_NODES] = run;
}

__global__ void permute_kernel(const int* __restrict__ ei, int* __restrict__ cursor,
                               int* __restrict__ perm) {
    int e = blockIdx.x * 256 + threadIdx.x;
    if (e < N_EDGES) {
        int d = ei[e];
        int pos = atomicAdd(&cursor[d], 1);
        perm[pos] = e;
    }
}

// ---------------------------------------------------------------------------
// Segmented aggregation: one wave per dest; cooperative edge prefetch kills
// the perm->ei->h serial chain. No atomics, no memset needed.
// ---------------------------------------------------------------------------
__global__ __launch_bounds__(256) void agg_csr_kernel(
    const float* __restrict__ h, const int* __restrict__ ei,
    const float* __restrict__ gates, const int* __restrict__ offs,
    const int* __restrict__ perm, float* __restrict__ agg)
{
    int d = (blockIdx.x * 256 + threadIdx.x) >> 6;
    if (d >= N_NODES) return;
    int lane = threadIdx.x & 63;
    int f = lane << 1;
    int hsel = f >> 4;
    int beg = offs[d], end = offs[d + 1];
    float ax = 0.f, ay = 0.f;
    for (int j0 = beg; j0 < end; j0 += 64) {
        int cnt = min(64, end - j0);
        int el = 0, sl = 0;
        if (lane < cnt) {
            el = perm[j0 + lane];
            sl = ei[N_EDGES + el];       // src
        }
        for (int i = 0; i < cnt; ++i) {
            int e = __shfl(el, i);
            int s = __shfl(sl, i);
            float gg = gates[(size_t)e * HEADS + hsel];
            float2 v = *(const float2*)(h + (size_t)s * HIDDEN + f);
            ax += v.x * gg;
            ay += v.y * gg;
        }
    }
    float2 o; o.x = ax; o.y = ay;
    *(float2*)(agg + (size_t)d * HIDDEN + f) = o;
}

// ---------------------------------------------------------------------------
// Fallback atomic scatter (tiny-ws only)
// ---------------------------------------------------------------------------
__global__ __launch_bounds__(256) void scatter_kernel(
    const float* __restrict__ h, const int* __restrict__ ei,
    const float* __restrict__ gates, float* __restrict__ agg)
{
    int gid = blockIdx.x * 256 + threadIdx.x;
    int e  = gid >> 5;
    int f0 = (gid & 31) << 2;
    int s = ei[N_EDGES + e];
    int d = ei[e];
    float g = gates[(size_t)e * HEADS + (f0 >> 4)];
    float4 v = *(const float4*)(h + (size_t)s * HIDDEN + f0);
    float* out = agg + (size_t)d * HIDDEN + f0;
    atomicAdd(out + 0, v.x * g);
    atomicAdd(out + 1, v.y * g);
    atomicAdd(out + 2, v.z * g);
    atomicAdd(out + 3, v.w * g);
}

// ---------------------------------------------------------------------------
// Projection: projected = agg @ Wout.T, in place over d_out proj region.
// ---------------------------------------------------------------------------
__global__ __launch_bounds__(256, 1) void proj_kernel(
    const float* __restrict__ Wout, float* __restrict__ out)
{
    __shared__ float wlds[HIDDEN][129];
    __shared__ float aggs[32][HIDDEN];
    const int tid = threadIdx.x;
    const int n0 = blockIdx.x * 32;

    for (int i = tid; i < HIDDEN * HIDDEN; i += 256)
        wlds[i >> 7][i & 127] = Wout[i];
    for (int i = tid; i < 32 * HIDDEN; i += 256) {
        int nl = i >> 7, f = i & 127;
        int n = n0 + nl;
        aggs[nl][f] = (n < N_NODES) ? out[(size_t)n * HIDDEN + f] : 0.f;
    }
    __syncthreads();

    for (int i = 0; i < 16; ++i) {
        int idx = tid + (i << 8);
        int nl = idx >> 7, o = idx & 127;
        float acc = 0.f;
        #pragma unroll 8
        for (int k = 0; k < HIDDEN; ++k) acc += aggs[nl][k] * wlds[o][k];
        int n = n0 + nl;
        if (n < N_NODES) out[(size_t)n * HIDDEN + o] = acc;
    }
}

// ---------------------------------------------------------------------------
extern "C" void kernel_launch(void* const* d_in, const int* in_sizes, int n_in,
                              void* d_out, int out_size, void* d_ws, size_t ws_size,
                              hipStream_t stream) {
    const float* h    = (const float*)d_in[0];
    const float* xs   = (const float*)d_in[1];
    const int*   ei   = (const int*)d_in[2];
    const float* ef   = (const float*)d_in[3];
    const float* W1   = (const float*)d_in[4];
    const float* W2   = (const float*)d_in[5];
    const float* Wout = (const float*)d_in[6];

    float* proj_out  = (float*)d_out;                        // [N, 128]
    float* gates_out = proj_out + (size_t)N_NODES * HIDDEN;  // [E, 8]

    // workspace layout (16B-aligned offsets)
    const size_t OFF_WB1  = 0;          // 163840  (wb1p [256][320] bf16)
    const size_t OFF_WB2  = 163840;     // 8192    (wb2p [16][256] bf16)
    const size_t OFF_DEG  = 172032;     // 200064
    const size_t OFF_OFFS = 372096;     // 200064
    const size_t OFF_CUR  = 572160;     // 200064
    const size_t OFF_PERM = 772224;     // 3200000
    const size_t OFF_HB   = 3972224;    // 12800000
    const size_t OFF_XSB  = 16772224;   // 1600000
    const size_t OFF_EFB  = 18372224;   // 25600000
    const size_t NEED_FULL = 43972224;
    const size_t NEED_CSR  = 3972224;

    unsigned short* wb1p = (unsigned short*)((char*)d_ws + OFF_WB1);
    unsigned short* wb2p = (unsigned short*)((char*)d_ws + OFF_WB2);
    unsigned short* hbp  = (unsigned short*)((char*)d_ws + OFF_HB);
    unsigned short* xsbp = (unsigned short*)((char*)d_ws + OFF_XSB);
    unsigned short* efbp = (unsigned short*)((char*)d_ws + OFF_EFB);

    const bool pre = ws_size >= NEED_FULL;
    const bool csr = ws_size >= NEED_CSR;

    prep_weights_kernel<<<42, 256, 0, stream>>>(W1, W2, wb1p, wb2p);
    if (pre) {
        prep_data_kernel<<<(HB_G + XSB_G + EFB_G + 255) / 256, 256, 0, stream>>>(
            h, xs, ef, hbp, xsbp, efbp);
        mlp_gates_kernel<true><<<NB, 256, 0, stream>>>(
            h, xs, ei, ef, wb1p, wb2p, hbp, xsbp, efbp, gates_out);
    } else {
        mlp_gates_kernel<false><<<NB, 256, 0, stream>>>(
            h, xs, ei, ef, wb1p, wb2p, hbp, xsbp, efbp, gates_out);
    }

    if (csr) {
        int* deg    = (int*)((char*)d_ws + OFF_DEG);
        int* offs   = (int*)((char*)d_ws + OFF_OFFS);
        int* cursor = (int*)((char*)d_ws + OFF_CUR);
        int* perm   = (int*)((char*)d_ws + OFF_PERM);

        hipMemsetAsync(deg, 0, N_NODES * sizeof(int), stream);
        hist_kernel<<<(N_EDGES + 255) / 256, 256, 0, stream>>>(ei, deg);
        scan_kernel<<<1, SCAN_T, 0, stream>>>(deg, offs, cursor);
        permute_kernel<<<(N_EDGES + 255) / 256, 256, 0, stream>>>(ei, cursor, perm);
        agg_csr_kernel<<<(N_NODES * 64 + 255) / 256, 256, 0, stream>>>(
            h, ei, gates_out, offs, perm, proj_out);
    } else {
        hipMemsetAsync(proj_out, 0, (size_t)N_NODES * HIDDEN * sizeof(float), stream);
        scatter_kernel<<<(N_EDGES * 32) / 256, 256, 0, stream>>>(h, ei, gates_out, proj_out);
    }

    proj_kernel<<<(N_NODES + 31) / 32, 256, 0, stream>>>(Wout, proj_out);
}

// Round 5
// 849.625 us; speedup vs baseline: 3.4996x; 1.2302x over previous
//
#include <hip/hip_runtime.h>
#include <hip/hip_bf16.h>

#define N_NODES 50000
#define N_EDGES 800000
#define HIDDEN 128
#define STATIC 16
#define EDGE_F 16
#define HEADS 8
#define KIN 304       // 2*128 + 2*16 + 16
#define KPAD 320      // KIN padded to multiple of 32
#define WID 256
#define TILE 64       // edges per tile
#define NTILES (N_EDGES / TILE)   // 12500
#define NB 512        // persistent blocks for mlp

typedef short bf16x8 __attribute__((ext_vector_type(8)));
typedef unsigned short u16x4 __attribute__((ext_vector_type(4)));
typedef unsigned short u16x8 __attribute__((ext_vector_type(8)));
typedef float f32x4 __attribute__((ext_vector_type(4)));

__device__ __forceinline__ unsigned short f2bf(float x) {
    __hip_bfloat16 b = __float2bfloat16(x);
    return __builtin_bit_cast(unsigned short, b);
}
__device__ __forceinline__ float bflo(unsigned int v) {   // low u16 as bf16 -> f32
    return __builtin_bit_cast(float, v << 16);
}
__device__ __forceinline__ float bfhi(unsigned int v) {   // high u16 as bf16 -> f32
    return __builtin_bit_cast(float, v & 0xffff0000u);
}

// ---------------------------------------------------------------------------
// prep_weights: W1 -> wb1p[256][320] bf16 (zero-padded), W2 -> wb2p[16][256],
//               Wout -> wob[128][128]
// ---------------------------------------------------------------------------
__global__ void prep_weights_kernel(const float* __restrict__ W1,
                                    const float* __restrict__ W2,
                                    const float* __restrict__ Wout,
                                    unsigned short* __restrict__ wb1p,
                                    unsigned short* __restrict__ wb2p,
                                    unsigned short* __restrict__ wob) {
    int gi = blockIdx.x * 256 + threadIdx.x;    // 8-elem group id, 12800 total
    if (gi < WID * (KPAD / 8)) {                // 10240 groups: W1
        int row = gi / 40, kg = gi - row * 40;
        u16x8 o = (u16x8)0;
        if (kg < 38) {                          // 38*8 = 304 = KIN exactly
            const float* s = W1 + (size_t)row * KIN + kg * 8;
            #pragma unroll
            for (int i = 0; i < 8; ++i) o[i] = f2bf(s[i]);
        }
        *(u16x8*)(wb1p + (size_t)gi * 8) = o;
        return;
    }
    int gj = gi - WID * (KPAD / 8);
    if (gj < 512) {                             // W2: [16][256], rows 8..15 zero
        int row = gj >> 5, kg = gj & 31;
        u16x8 o = (u16x8)0;
        if (row < HEADS) {
            const float* s = W2 + (size_t)row * WID + kg * 8;
            #pragma unroll
            for (int i = 0; i < 8; ++i) o[i] = f2bf(s[i]);
        }
        *(u16x8*)(wb2p + (size_t)gj * 8) = o;
        return;
    }
    int gk = gj - 512;
    if (gk < 2048) {                            // Wout: [128][128]
        int row = gk >> 4, kg = gk & 15;
        const float* s = Wout + (size_t)row * HIDDEN + kg * 8;
        u16x8 o;
        #pragma unroll
        for (int i = 0; i < 8; ++i) o[i] = f2bf(s[i]);
        *(u16x8*)(wob + (size_t)gk * 8) = o;
    }
}

// ---------------------------------------------------------------------------
// prep_data: h, xs fp32 -> bf16 (ef stays fp32: read-once data)
// ---------------------------------------------------------------------------
#define HB_G  (N_NODES * HIDDEN / 8)    // 800000
#define XSB_G (N_NODES * STATIC / 8)    // 100000
__global__ void prep_data_kernel(const float* __restrict__ h,
                                 const float* __restrict__ xs,
                                 unsigned short* __restrict__ hb,
                                 unsigned short* __restrict__ xsb) {
    size_t gi = (size_t)blockIdx.x * 256 + threadIdx.x;
    const float* s;
    unsigned short* d;
    if (gi < HB_G)              { s = h  + gi * 8;        d = hb  + gi * 8; }
    else if (gi < HB_G + XSB_G) { size_t k = gi - HB_G;   s = xs + k * 8; d = xsb + k * 8; }
    else return;
    u16x8 o;
    #pragma unroll
    for (int i = 0; i < 8; ++i) o[i] = f2bf(s[i]);
    *(u16x8*)d = o;
}

// ---------------------------------------------------------------------------
// MLP: weight-stationary register GEMM. waves_per_eu pinned to 2 so the
// allocator gets the full 256-VGPR budget (LDS caps occupancy at 2 blocks/CU
// = 2 waves/SIMD anyway; the round-4 128-VGPR allocation spilled the 192
// VGPRs of register-resident W1/W2 and cost 15x in the k-loop).
// ---------------------------------------------------------------------------
template <bool PRE>
__global__ __attribute__((amdgpu_flat_work_group_size(256, 256), amdgpu_waves_per_eu(2, 2)))
void mlp_gates_kernel(
    const float* __restrict__ hf, const float* __restrict__ xsf,
    const int* __restrict__ ei, const float* __restrict__ eff,
    const unsigned short* __restrict__ wb1p, const unsigned short* __restrict__ wb2p,
    const unsigned short* __restrict__ hb, const unsigned short* __restrict__ xsb,
    float* __restrict__ gates_out)
{
    __shared__ __align__(16) short A_sh[TILE * KPAD];    // 40960 B, row=640 B swizzled
    __shared__ __align__(16) short hid_sh[TILE * WID];   // 32768 B, row=512 B swizzled
    __shared__ int src_s[TILE], dst_s[TILE];

    const int tid  = threadIdx.x;
    const int lane = tid & 63;
    const int w    = tid >> 6;            // wave 0..3
    const int r    = lane & 15;
    const int g    = lane >> 4;
    const int xorv = (r & 7) << 4;        // T2 swizzle term for frag reads

    // ---- register-stationary weights: W1 frags 160 VGPR, W2 frags 32 VGPR ----
    bf16x8 b1[4][10];
    #pragma unroll
    for (int t = 0; t < 4; ++t)
        #pragma unroll
        for (int ks = 0; ks < 10; ++ks)
            b1[t][ks] = *(const bf16x8*)(wb1p + (size_t)((w * 4 + t) * 16 + r) * KPAD + ks * 32 + g * 8);
    bf16x8 w2f[8];
    #pragma unroll
    for (int k2 = 0; k2 < 8; ++k2)
        w2f[k2] = *(const bf16x8*)(wb2p + (size_t)r * WID + k2 * 32 + g * 8);

    int tile = blockIdx.x;
    if (tid < TILE && tile < NTILES) {
        src_s[tid] = ei[N_EDGES + tile * TILE + tid];   // src = edge_index[1]
        dst_s[tid] = ei[tile * TILE + tid];             // dest = edge_index[0]
    }
    __syncthreads();

    for (; tile < NTILES; tile += NB) {
        const int e0 = tile * TILE;

        // ---- gather mlp_input -> A_sh (bf16, swizzled) ----
        if (PRE) {
            const u16x8* h8  = (const u16x8*)hb;
            const u16x8* xs8 = (const u16x8*)xsb;
            #pragma unroll
            for (int idx = tid; idx < 1024; idx += 256) {       // h[src]: elems 0..127
                int e = idx >> 4, c = idx & 15;
                u16x8 v = h8[(size_t)src_s[e] * 16 + c];
                *(u16x8*)((char*)A_sh + e * 640 + (((c << 4)) ^ ((e & 7) << 4))) = v;
            }
            #pragma unroll
            for (int idx = tid; idx < 1024; idx += 256) {       // h[dest]: elems 128..255
                int e = idx >> 4, c = idx & 15;
                u16x8 v = h8[(size_t)dst_s[e] * 16 + c];
                *(u16x8*)((char*)A_sh + e * 640 + ((256 + (c << 4)) ^ ((e & 7) << 4))) = v;
            }
            #pragma unroll
            for (int idx = tid; idx < 512; idx += 256) {        // xs/ef/zero: elems 256..319
                int e = idx >> 3, c = idx & 7;
                u16x8 v = (u16x8)0;
                if (c < 2)      v = xs8[(size_t)src_s[e] * 2 + c];
                else if (c < 4) v = xs8[(size_t)dst_s[e] * 2 + (c - 2)];
                else if (c < 6) {
                    const float4* p = (const float4*)(eff + (size_t)(e0 + e) * EDGE_F + (c - 4) * 8);
                    float4 v0 = p[0], v1 = p[1];
                    v[0] = f2bf(v0.x); v[1] = f2bf(v0.y); v[2] = f2bf(v0.z); v[3] = f2bf(v0.w);
                    v[4] = f2bf(v1.x); v[5] = f2bf(v1.y); v[6] = f2bf(v1.z); v[7] = f2bf(v1.w);
                }
                *(u16x8*)((char*)A_sh + e * 640 + ((512 + (c << 4)) ^ ((e & 7) << 4))) = v;
            }
        } else {
            const float4* h4  = (const float4*)hf;
            const float4* xs4 = (const float4*)xsf;
            const float4* ef4 = (const float4*)eff;
            #pragma unroll
            for (int idx = tid; idx < 2048; idx += 256) {       // h[src]
                int e = idx >> 5, q = idx & 31;
                float4 v = h4[(size_t)src_s[e] * 32 + q];
                u16x4 p; p[0] = f2bf(v.x); p[1] = f2bf(v.y); p[2] = f2bf(v.z); p[3] = f2bf(v.w);
                *(u16x4*)((char*)A_sh + e * 640 + (((q << 3)) ^ ((e & 7) << 4))) = p;
            }
            #pragma unroll
            for (int idx = tid; idx < 2048; idx += 256) {       // h[dest]
                int e = idx >> 5, q = idx & 31;
                float4 v = h4[(size_t)dst_s[e] * 32 + q];
                u16x4 p; p[0] = f2bf(v.x); p[1] = f2bf(v.y); p[2] = f2bf(v.z); p[3] = f2bf(v.w);
                *(u16x4*)((char*)A_sh + e * 640 + ((256 + (q << 3)) ^ ((e & 7) << 4))) = p;
            }
            #pragma unroll
            for (int idx = tid; idx < 1024; idx += 256) {       // xs/ef/zero
                int e = idx >> 4, c = idx & 15;
                float4 v = make_float4(0.f, 0.f, 0.f, 0.f);
                if (c < 4)       v = xs4[(size_t)src_s[e] * 4 + c];
                else if (c < 8)  v = xs4[(size_t)dst_s[e] * 4 + (c - 4)];
                else if (c < 12) v = ef4[(size_t)(e0 + e) * 4 + (c - 8)];
                u16x4 p; p[0] = f2bf(v.x); p[1] = f2bf(v.y); p[2] = f2bf(v.z); p[3] = f2bf(v.w);
                *(u16x4*)((char*)A_sh + e * 640 + ((512 + (c << 3)) ^ ((e & 7) << 4))) = p;
            }
        }
        __syncthreads();                                        // B1: A ready

        // preload next tile's indices (latency hides under GEMM1)
        int nsrc = 0, ndst = 0;
        const int ntile = tile + NB;
        const bool more = (ntile < NTILES);
        if (tid < TILE && more) {
            nsrc = ei[N_EDGES + ntile * TILE + tid];
            ndst = ei[ntile * TILE + tid];
        }

        // ---- GEMM1: 4 edge-subtiles x 4 unit-tiles x 10 k-chunks ----
        #pragma unroll
        for (int sub = 0; sub < 4; ++sub) {
            f32x4 acc[4];
            #pragma unroll
            for (int t = 0; t < 4; ++t) acc[t] = (f32x4)(0.f);
            const char* abase = (const char*)A_sh + (sub * 16 + r) * 640;
            #pragma unroll
            for (int ks = 0; ks < 10; ++ks) {
                bf16x8 a = *(const bf16x8*)(abase + (((ks << 6) | (g << 4)) ^ xorv));
                #pragma unroll
                for (int t = 0; t < 4; ++t)
                    acc[t] = __builtin_amdgcn_mfma_f32_16x16x32_bf16(a, b1[t][ks], acc[t], 0, 0, 0);
            }
            // relu + bf16 -> hid (C/D: col=lane&15 -> unit, row=g*4+q -> edge)
            #pragma unroll
            for (int t = 0; t < 4; ++t)
                #pragma unroll
                for (int q = 0; q < 4; ++q) {
                    int e = sub * 16 + g * 4 + q;
                    int n = (w * 4 + t) * 16 + r;
                    *(short*)((char*)hid_sh + e * 512 + ((n * 2) ^ ((e & 7) << 4))) =
                        (short)f2bf(fmaxf(acc[t][q], 0.f));
                }
        }
        if (tid < TILE && more) { src_s[tid] = nsrc; dst_s[tid] = ndst; }
        __syncthreads();                                        // B2: hid + indices ready

        // ---- GEMM2: wave w does its 16-edge subtile vs W2 frags ----
        f32x4 sacc = (f32x4)(0.f);
        const char* hbase = (const char*)hid_sh + (w * 16 + r) * 512;
        #pragma unroll
        for (int k2 = 0; k2 < 8; ++k2) {
            bf16x8 a2 = *(const bf16x8*)(hbase + (((k2 << 6) | (g << 4)) ^ xorv));
            sacc = __builtin_amdgcn_mfma_f32_16x16x32_bf16(a2, w2f[k2], sacc, 0, 0, 0);
        }
        if (r < HEADS) {
            #pragma unroll
            for (int q = 0; q < 4; ++q) {
                int e = e0 + w * 16 + g * 4 + q;
                gates_out[(size_t)e * HEADS + r] = 1.f / (1.f + __expf(-sacc[q]));
            }
        }
    }
}

// ---------------------------------------------------------------------------
// CSR build
// ---------------------------------------------------------------------------
__global__ void hist_kernel(const int* __restrict__ ei, int* __restrict__ deg) {
    int e = blockIdx.x * 256 + threadIdx.x;
    if (e < N_EDGES) atomicAdd(&deg[ei[e]], 1);
}

#define SCAN_T 1024
#define SCAN_CHUNK 49   // 1024*49 = 50176 >= 50000
__global__ __launch_bounds__(SCAN_T) void scan_kernel(
    const int* __restrict__ deg, int* __restrict__ offs, int* __restrict__ cursor) {
    __shared__ int part[SCAN_T];
    int t = threadIdx.x;
    int b = t * SCAN_CHUNK;
    int s = 0;
    for (int i = 0; i < SCAN_CHUNK; ++i) {
        int idx = b + i;
        if (idx < N_NODES) s += deg[idx];
    }
    part[t] = s;
    __syncthreads();
    for (int off = 1; off < SCAN_T; off <<= 1) {
        int v = (t >= off) ? part[t - off] : 0;
        __syncthreads();
        part[t] += v;
        __syncthreads();
    }
    int run = (t == 0) ? 0 : part[t - 1];
    for (int i = 0; i < SCAN_CHUNK; ++i) {
        int idx = b + i;
        if (idx < N_NODES) {
            int dv = deg[idx];
            offs[idx] = run;
            cursor[idx] = run;
            run += dv;
        }
    }
    if (t == SCAN_T - 1) offs[N_NODES] = run;
}

__global__ void permute_kernel(const int* __restrict__ ei, int* __restrict__ cursor,
                               int* __restrict__ perm) {
    int e = blockIdx.x * 256 + threadIdx.x;
    if (e < N_EDGES) {
        int d = ei[e];
        int pos = atomicAdd(&cursor[d], 1);
        perm[pos] = e;
    }
}

// ---------------------------------------------------------------------------
// Segmented aggregation: one wave per dest; bf16 h rows (half traffic),
// manual 4-deep load pipeline (dynamic-trip loop won't unroll on its own).
// Writes bf16 aggb for the MFMA projection.
// ---------------------------------------------------------------------------
__global__ __launch_bounds__(256) void agg_csr_kernel(
    const unsigned short* __restrict__ hb, const int* __restrict__ ei,
    const float* __restrict__ gates, const int* __restrict__ offs,
    const int* __restrict__ perm, unsigned short* __restrict__ aggb)
{
    int d = (blockIdx.x * 256 + threadIdx.x) >> 6;
    if (d >= N_NODES) return;
    int lane = threadIdx.x & 63;
    int f = lane << 1;
    int hsel = f >> 4;
    int beg = offs[d], end = offs[d + 1];
    float ax = 0.f, ay = 0.f;
    for (int j0 = beg; j0 < end; j0 += 64) {
        int cnt = min(64, end - j0);
        int el = 0, sl = 0;
        if (lane < cnt) {
            el = perm[j0 + lane];
            sl = ei[N_EDGES + el];       // src
        }
        int i = 0;
        for (; i + 4 <= cnt; i += 4) {
            float gv[4];
            unsigned int hv[4];
            #pragma unroll
            for (int k = 0; k < 4; ++k) {
                int e = __shfl(el, i + k);
                int s = __shfl(sl, i + k);
                gv[k] = gates[(size_t)e * HEADS + hsel];
                hv[k] = *(const unsigned int*)(hb + (size_t)s * HIDDEN + f);
            }
            #pragma unroll
            for (int k = 0; k < 4; ++k) {
                ax += bflo(hv[k]) * gv[k];
                ay += bfhi(hv[k]) * gv[k];
            }
        }
        for (; i < cnt; ++i) {
            int e = __shfl(el, i);
            int s = __shfl(sl, i);
            float gg = gates[(size_t)e * HEADS + hsel];
            unsigned int hv = *(const unsigned int*)(hb + (size_t)s * HIDDEN + f);
            ax += bflo(hv) * gg;
            ay += bfhi(hv) * gg;
        }
    }
    unsigned int o = ((unsigned int)f2bf(ay) << 16) | (unsigned int)f2bf(ax);
    *(unsigned int*)(aggb + (size_t)d * HIDDEN + f) = o;
}

// ---------------------------------------------------------------------------
// Projection via MFMA: out[64 nodes][128] = aggb @ wob^T per block.
// ---------------------------------------------------------------------------
__global__ __launch_bounds__(256) void proj_mfma_kernel(
    const unsigned short* __restrict__ aggb, const unsigned short* __restrict__ wob,
    float* __restrict__ out)
{
    __shared__ __align__(16) short A_sh[64 * 128];   // 16 KB, 256 B rows, swizzled
    const int tid = threadIdx.x, lane = tid & 63, w = tid >> 6;
    const int r = lane & 15, g = lane >> 4;
    const int xorv = (r & 7) << 4;
    const int n0 = blockIdx.x * 64;

    bf16x8 b[2][4];
    #pragma unroll
    for (int t = 0; t < 2; ++t)
        #pragma unroll
        for (int ks = 0; ks < 4; ++ks)
            b[t][ks] = *(const bf16x8*)(wob + (size_t)((w * 2 + t) * 16 + r) * HIDDEN + ks * 32 + g * 8);

    for (int idx = tid; idx < 1024; idx += 256) {
        int e = idx >> 4, c = idx & 15;
        int n = n0 + e;
        u16x8 v = (u16x8)0;
        if (n < N_NODES) v = *(const u16x8*)(aggb + (size_t)n * HIDDEN + c * 8);
        *(u16x8*)((char*)A_sh + e * 256 + ((c << 4) ^ ((e & 7) << 4))) = v;
    }
    __syncthreads();

    #pragma unroll
    for (int sub = 0; sub < 4; ++sub) {
        f32x4 acc[2];
        acc[0] = (f32x4)(0.f); acc[1] = (f32x4)(0.f);
        const char* abase = (const char*)A_sh + (sub * 16 + r) * 256;
        #pragma unroll
        for (int ks = 0; ks < 4; ++ks) {
            bf16x8 a = *(const bf16x8*)(abase + (((ks << 6) | (g << 4)) ^ xorv));
            acc[0] = __builtin_amdgcn_mfma_f32_16x16x32_bf16(a, b[0][ks], acc[0], 0, 0, 0);
            acc[1] = __builtin_amdgcn_mfma_f32_16x16x32_bf16(a, b[1][ks], acc[1], 0, 0, 0);
        }
        #pragma unroll
        for (int t = 0; t < 2; ++t)
            #pragma unroll
            for (int q = 0; q < 4; ++q) {
                int n = n0 + sub * 16 + g * 4 + q;
                if (n < N_NODES)
                    out[(size_t)n * HIDDEN + (w * 2 + t) * 16 + r] = acc[t][q];
            }
    }
}

// ---------------------------------------------------------------------------
// Fallback path kernels (tiny workspace only)
// ---------------------------------------------------------------------------
__global__ __launch_bounds__(256) void scatter_kernel(
    const float* __restrict__ h, const int* __restrict__ ei,
    const float* __restrict__ gates, float* __restrict__ agg)
{
    int gid = blockIdx.x * 256 + threadIdx.x;
    int e  = gid >> 5;
    int f0 = (gid & 31) << 2;
    int s = ei[N_EDGES + e];
    int d = ei[e];
    float g = gates[(size_t)e * HEADS + (f0 >> 4)];
    float4 v = *(const float4*)(h + (size_t)s * HIDDEN + f0);
    float* out = agg + (size_t)d * HIDDEN + f0;
    atomicAdd(out + 0, v.x * g);
    atomicAdd(out + 1, v.y * g);
    atomicAdd(out + 2, v.z * g);
    atomicAdd(out + 3, v.w * g);
}

__global__ __launch_bounds__(256, 1) void proj_kernel(
    const float* __restrict__ Wout, float* __restrict__ out)
{
    __shared__ float wlds[HIDDEN][129];
    __shared__ float aggs[32][HIDDEN];
    const int tid = threadIdx.x;
    const int n0 = blockIdx.x * 32;

    for (int i = tid; i < HIDDEN * HIDDEN; i += 256)
        wlds[i >> 7][i & 127] = Wout[i];
    for (int i = tid; i < 32 * HIDDEN; i += 256) {
        int nl = i >> 7, f = i & 127;
        int n = n0 + nl;
        aggs[nl][f] = (n < N_NODES) ? out[(size_t)n * HIDDEN + f] : 0.f;
    }
    __syncthreads();

    for (int i = 0; i < 16; ++i) {
        int idx = tid + (i << 8);
        int nl = idx >> 7, o = idx & 127;
        float acc = 0.f;
        #pragma unroll 8
        for (int k = 0; k < HIDDEN; ++k) acc += aggs[nl][k] * wlds[o][k];
        int n = n0 + nl;
        if (n < N_NODES) out[(size_t)n * HIDDEN + o] = acc;
    }
}

// ---------------------------------------------------------------------------
extern "C" void kernel_launch(void* const* d_in, const int* in_sizes, int n_in,
                              void* d_out, int out_size, void* d_ws, size_t ws_size,
                              hipStream_t stream) {
    const float* h    = (const float*)d_in[0];
    const float* xs   = (const float*)d_in[1];
    const int*   ei   = (const int*)d_in[2];
    const float* ef   = (const float*)d_in[3];
    const float* W1   = (const float*)d_in[4];
    const float* W2   = (const float*)d_in[5];
    const float* Wout = (const float*)d_in[6];

    float* proj_out  = (float*)d_out;                        // [N, 128]
    float* gates_out = proj_out + (size_t)N_NODES * HIDDEN;  // [E, 8]

    // workspace layout (16B-aligned offsets)
    const size_t OFF_WB1  = 0;          // 163840
    const size_t OFF_WB2  = 163840;     // 8192
    const size_t OFF_WOB  = 172032;     // 32768
    const size_t OFF_DEG  = 204800;     // 200704
    const size_t OFF_OFFS = 405504;     // 200704
    const size_t OFF_CUR  = 606208;     // 200704
    const size_t OFF_PERM = 806912;     // 3200000
    const size_t OFF_AGGB = 4006912;    // 12800000
    const size_t OFF_HB   = 16806912;   // 12800000
    const size_t OFF_XSB  = 29606912;   // 1600000
    const size_t NEED_FULL = 31206912;

    unsigned short* wb1p = (unsigned short*)((char*)d_ws + OFF_WB1);
    unsigned short* wb2p = (unsigned short*)((char*)d_ws + OFF_WB2);
    unsigned short* wob  = (unsigned short*)((char*)d_ws + OFF_WOB);
    unsigned short* aggb = (unsigned short*)((char*)d_ws + OFF_AGGB);
    unsigned short* hbp  = (unsigned short*)((char*)d_ws + OFF_HB);
    unsigned short* xsbp = (unsigned short*)((char*)d_ws + OFF_XSB);

    prep_weights_kernel<<<50, 256, 0, stream>>>(W1, W2, Wout, wb1p, wb2p, wob);

    if (ws_size >= NEED_FULL) {
        int* deg    = (int*)((char*)d_ws + OFF_DEG);
        int* offs   = (int*)((char*)d_ws + OFF_OFFS);
        int* cursor = (int*)((char*)d_ws + OFF_CUR);
        int* perm   = (int*)((char*)d_ws + OFF_PERM);

        prep_data_kernel<<<(HB_G + XSB_G + 255) / 256, 256, 0, stream>>>(h, xs, hbp, xsbp);
        mlp_gates_kernel<true><<<NB, 256, 0, stream>>>(
            h, xs, ei, ef, wb1p, wb2p, hbp, xsbp, gates_out);

        hipMemsetAsync(deg, 0, N_NODES * sizeof(int), stream);
        hist_kernel<<<(N_EDGES + 255) / 256, 256, 0, stream>>>(ei, deg);
        scan_kernel<<<1, SCAN_T, 0, stream>>>(deg, offs, cursor);
        permute_kernel<<<(N_EDGES + 255) / 256, 256, 0, stream>>>(ei, cursor, perm);
        agg_csr_kernel<<<(N_NODES * 64 + 255) / 256, 256, 0, stream>>>(
            hbp, ei, gates_out, offs, perm, aggb);
        proj_mfma_kernel<<<(N_NODES + 63) / 64, 256, 0, stream>>>(aggb, wob, proj_out);
    } else {
        mlp_gates_kernel<false><<<NB, 256, 0, stream>>>(
            h, xs, ei, ef, wb1p, wb2p, nullptr, nullptr, gates_out);
        hipMemsetAsync(proj_out, 0, (size_t)N_NODES * HIDDEN * sizeof(float), stream);
        scatter_kernel<<<(N_EDGES * 32) / 256, 256, 0, stream>>>(h, ei, gates_out, proj_out);
        proj_kernel<<<(N_NODES + 31) / 32, 256, 0, stream>>>(Wout, proj_out);
    }
}